// Round 1
// baseline (319.685 us; speedup 1.0000x reference)
//
#include <hip/hip_runtime.h>

// GateSparsemaxK: per-row (R=4096) gated sparsemax, scaled by k, clipped to [0,1].
// z = where(mask>0.5, s, -1e9)/0.7 ; p = sparsemax(z) ; out = min(k*p, 1)
//
// Strategy: one wave (64 lanes) per row, 64 elements/lane in registers.
// Sparsemax threshold via Michelot's algorithm (exact, no sort):
//   tau0 = max(z) - 1                      (guaranteed <= tau*)
//   tau  <- (sum_{z>tau} z - 1) / #{z>tau} (monotone up, support shrinks)
//   stop when tau is a fixed point (support stabilized) -> exact tau*.
// All reductions are wave-level __shfl_xor butterflies; no LDS, no syncthreads.

#define R_DIM 4096
#define LANES 64
#define EPT (R_DIM / LANES)      // 64 elements per lane
#define WAVES_PER_BLOCK 4        // block = 256 threads = 4 independent rows
#define BIG_NEG -1.0e9f
#define INV_TAU (1.0f / 0.7f)

__global__ __launch_bounds__(256, 4)
void gate_sparsemax_k_kernel(const float* __restrict__ s,
                             const float* __restrict__ m,
                             const int*  __restrict__ kptr,
                             float* __restrict__ out,
                             int nrows)
{
    const int lane = (int)(threadIdx.x & 63u);
    const int wid  = (int)(threadIdx.x >> 6);
    const int row  = blockIdx.x * WAVES_PER_BLOCK + wid;
    if (row >= nrows) return;

    const float kf = (float)(*kptr);

    const size_t base = (size_t)row * R_DIM;
    const float4* sv4 = (const float4*)(s + base);
    const float4* mv4 = (const float4*)(m + base);
    float4*       ov4 = (float4*)(out + base);

    // ---- load + gate + scale; track row max -------------------------------
    float z[EPT];
    float zmax = -3.4028235e38f;

    #pragma unroll
    for (int c = 0; c < EPT / 4; ++c) {       // 16 float4 chunks, coalesced
        const int idx = c * LANES + lane;     // lane-contiguous 16B/lane
        const float4 sv = sv4[idx];
        const float4 mv = mv4[idx];
        const float z0 = (mv.x > 0.5f ? sv.x : BIG_NEG) * INV_TAU;
        const float z1 = (mv.y > 0.5f ? sv.y : BIG_NEG) * INV_TAU;
        const float z2 = (mv.z > 0.5f ? sv.z : BIG_NEG) * INV_TAU;
        const float z3 = (mv.w > 0.5f ? sv.w : BIG_NEG) * INV_TAU;
        z[c * 4 + 0] = z0;
        z[c * 4 + 1] = z1;
        z[c * 4 + 2] = z2;
        z[c * 4 + 3] = z3;
        zmax = fmaxf(zmax, fmaxf(fmaxf(z0, z1), fmaxf(z2, z3)));
    }

    // wave-wide max (butterfly -> all lanes hold the max)
    #pragma unroll
    for (int off = 32; off >= 1; off >>= 1)
        zmax = fmaxf(zmax, __shfl_xor(zmax, off, 64));

    // ---- Michelot iterations (exact sparsemax threshold) ------------------
    float tau = zmax - 1.0f;
    for (int it = 0; it < 100; ++it) {
        float ssum = 0.0f;
        float cnt  = 0.0f;
        #pragma unroll
        for (int e = 0; e < EPT; ++e) {
            const float zv = z[e];
            const bool b = zv > tau;
            ssum += b ? zv : 0.0f;
            cnt  += b ? 1.0f : 0.0f;
        }
        #pragma unroll
        for (int off = 32; off >= 1; off >>= 1) {
            ssum += __shfl_xor(ssum, off, 64);
            cnt  += __shfl_xor(cnt,  off, 64);
        }
        const float tnew = (ssum - 1.0f) / cnt;   // cnt >= 1 always (max in support)
        if (tnew == tau) break;                   // wave-uniform: exact fixed point
        tau = tnew;
    }

    // ---- epilogue: p = max(z - tau, 0); out = min(k*p, 1) -----------------
    #pragma unroll
    for (int c = 0; c < EPT / 4; ++c) {
        const int idx = c * LANES + lane;
        float4 ov;
        ov.x = fminf(kf * fmaxf(z[c * 4 + 0] - tau, 0.0f), 1.0f);
        ov.y = fminf(kf * fmaxf(z[c * 4 + 1] - tau, 0.0f), 1.0f);
        ov.z = fminf(kf * fmaxf(z[c * 4 + 2] - tau, 0.0f), 1.0f);
        ov.w = fminf(kf * fmaxf(z[c * 4 + 3] - tau, 0.0f), 1.0f);
        ov4[idx] = ov;
    }
}

extern "C" void kernel_launch(void* const* d_in, const int* in_sizes, int n_in,
                              void* d_out, int out_size, void* d_ws, size_t ws_size,
                              hipStream_t stream) {
    const float* s = (const float*)d_in[0];
    const float* m = (const float*)d_in[1];
    const int*   k = (const int*)d_in[2];
    float* out = (float*)d_out;

    const int nrows = in_sizes[0] / R_DIM;                 // 8192
    const int blocks = (nrows + WAVES_PER_BLOCK - 1) / WAVES_PER_BLOCK;  // 2048

    gate_sparsemax_k_kernel<<<blocks, 256, 0, stream>>>(s, m, k, out, nrows);
}

// Round 2
// 319.363 us; speedup vs baseline: 1.0010x; 1.0010x over previous
//
#include <hip/hip_runtime.h>

// GateSparsemaxK: per-row (R=4096) gated sparsemax, scaled by k, clipped to [0,1].
// z = where(mask>0.5, s, -1e9)/0.7 ; p = sparsemax(z) ; out = min(k*p, 1)
//
// R1 lesson: z[64] per-lane register array got demoted (VGPR_Count=64 => AGPR/scratch
// shuffling, latency-bound at 119us, VALUBusy 18%, HBM 30%). This version stores the
// row in LDS instead: one wave per row, 4 rows per 256-thread block, 64 KB LDS.
// No barriers (each row touched by exactly one wave). Michelot threshold iterations
// scan LDS (expected ~2-4 iters; support is tiny for gated Gaussian rows).

#define R_DIM 4096
#define LANES 64
#define CHUNKS (R_DIM / (LANES * 4))   // 16 float4 chunks per lane
#define ROWS_PER_BLOCK 4
#define BIG_NEG -1.0e9f
#define INV_TAU (1.0f / 0.7f)

__global__ __launch_bounds__(256, 2)
void gate_sparsemax_k_kernel(const float* __restrict__ s,
                             const float* __restrict__ m,
                             const int*  __restrict__ kptr,
                             float* __restrict__ out,
                             int nrows)
{
    __shared__ float zs[ROWS_PER_BLOCK][R_DIM];   // 64 KB

    const int lane = (int)(threadIdx.x & 63u);
    const int wid  = (int)(threadIdx.x >> 6);
    const int row  = blockIdx.x * ROWS_PER_BLOCK + wid;
    if (row >= nrows) return;

    const float kf = (float)(*kptr);

    const size_t base = (size_t)row * R_DIM;
    const float4* sv4 = (const float4*)(s + base);
    const float4* mv4 = (const float4*)(m + base);
    float4*       ov4 = (float4*)(out + base);
    float4*       zr4 = (float4*)(zs[wid]);

    // ---- phase 1: load + gate + scale -> LDS; fused row-max ---------------
    float zmax = -3.4028235e38f;
    #pragma unroll
    for (int c = 0; c < CHUNKS; ++c) {
        const int idx = c * LANES + lane;          // float4 index, lane-contiguous
        const float4 sv = sv4[idx];
        const float4 mv = mv4[idx];
        float4 zv;
        zv.x = (mv.x > 0.5f ? sv.x : BIG_NEG) * INV_TAU;
        zv.y = (mv.y > 0.5f ? sv.y : BIG_NEG) * INV_TAU;
        zv.z = (mv.z > 0.5f ? sv.z : BIG_NEG) * INV_TAU;
        zv.w = (mv.w > 0.5f ? sv.w : BIG_NEG) * INV_TAU;
        zr4[idx] = zv;                             // ds_write_b128, stride-1
        zmax = fmaxf(zmax, fmaxf(fmaxf(zv.x, zv.y), fmaxf(zv.z, zv.w)));
    }

    // wave-wide max (butterfly; all lanes converge)
    #pragma unroll
    for (int off = 32; off >= 1; off >>= 1)
        zmax = fmaxf(zmax, __shfl_xor(zmax, off, 64));

    // ---- phase 2: Michelot iterations over LDS row ------------------------
    // tau0 = max - 1 <= tau*; tau <- (sum_{z>tau} z - 1)/#{z>tau} is monotone
    // non-decreasing and hits the exact fixed point tau* when support stops
    // shrinking (finite set + identical fp computation => equality => break).
    float tau = zmax - 1.0f;
    for (int it = 0; it < 50; ++it) {
        float ssum = 0.0f;
        float cnt  = 0.0f;
        #pragma unroll
        for (int c = 0; c < CHUNKS; ++c) {
            const float4 zv = zr4[c * LANES + lane];   // ds_read_b128
            if (zv.x > tau) { ssum += zv.x; cnt += 1.0f; }
            if (zv.y > tau) { ssum += zv.y; cnt += 1.0f; }
            if (zv.z > tau) { ssum += zv.z; cnt += 1.0f; }
            if (zv.w > tau) { ssum += zv.w; cnt += 1.0f; }
        }
        #pragma unroll
        for (int off = 32; off >= 1; off >>= 1) {
            ssum += __shfl_xor(ssum, off, 64);
            cnt  += __shfl_xor(cnt,  off, 64);
        }
        const float tnew = (ssum - 1.0f) / cnt;    // cnt >= 1 (max is in support)
        if (tnew == tau) break;                    // wave-uniform exact fixed point
        tau = tnew;
    }

    // ---- phase 3: epilogue p = max(z - tau, 0); out = min(k*p, 1) ---------
    #pragma unroll
    for (int c = 0; c < CHUNKS; ++c) {
        const int idx = c * LANES + lane;
        const float4 zv = zr4[idx];
        float4 ov;
        ov.x = fminf(kf * fmaxf(zv.x - tau, 0.0f), 1.0f);
        ov.y = fminf(kf * fmaxf(zv.y - tau, 0.0f), 1.0f);
        ov.z = fminf(kf * fmaxf(zv.z - tau, 0.0f), 1.0f);
        ov.w = fminf(kf * fmaxf(zv.w - tau, 0.0f), 1.0f);
        ov4[idx] = ov;
    }
}

extern "C" void kernel_launch(void* const* d_in, const int* in_sizes, int n_in,
                              void* d_out, int out_size, void* d_ws, size_t ws_size,
                              hipStream_t stream) {
    const float* s = (const float*)d_in[0];
    const float* m = (const float*)d_in[1];
    const int*   k = (const int*)d_in[2];
    float* out = (float*)d_out;

    const int nrows = in_sizes[0] / R_DIM;                       // 8192
    const int blocks = (nrows + ROWS_PER_BLOCK - 1) / ROWS_PER_BLOCK;  // 2048

    gate_sparsemax_k_kernel<<<blocks, 256, 0, stream>>>(s, m, k, out, nrows);
}

// Round 3
// 312.448 us; speedup vs baseline: 1.0232x; 1.0221x over previous
//
#include <hip/hip_runtime.h>

// GateSparsemaxK: per-row (R=4096) gated sparsemax, scaled by k, clipped to [0,1].
// z = where(mask>0.5, s, -1e9)/0.7 ; p = sparsemax(z) ; out = min(k*p, 1)
//
// R1/R2 lesson: one-wave-per-row forces the whole 16KB row into either registers
// (demoted -> scratch, R1) or 64KB LDS (2 blocks/CU, 17% occupancy, R2); both
// latency-bound at ~120us with VALUBusy 18% / HBM 27%. Fix is TLP:
//   - one ROW per 256-thread BLOCK (4 waves share the row)
//   - 16 elements/lane -> float4 zz[4] stays in VGPRs (~16 regs)
//   - LDS = 48 B of reduction scratch only -> occupancy VGPR-bound (~24 waves/CU)
// Michelot threshold iterations (exact, no sort): tau0 = max-1; tau <- (sum_{z>tau}-1)/cnt;
// monotone, support shrinks, terminates exactly at the fixed point (~2-4 iters).

#define R_DIM 4096
#define BLOCK 256
#define V4T   4                 // float4s per thread: 4096 / 4 / 256
#define BIG_NEG -1.0e9f
#define INV_TAU (1.0f / 0.7f)

__global__ __launch_bounds__(BLOCK, 6)
void gate_sparsemax_k_kernel(const float* __restrict__ s,
                             const float* __restrict__ m,
                             const int*  __restrict__ kptr,
                             float* __restrict__ out)
{
    __shared__ float red_sum[4];
    __shared__ float red_cnt[4];
    __shared__ float red_max[4];

    const int tid  = (int)threadIdx.x;
    const int lane = tid & 63;
    const int wid  = tid >> 6;
    const int row  = (int)blockIdx.x;

    const float kf = (float)(*kptr);

    const size_t base = (size_t)row * R_DIM;
    const float4* sv4 = (const float4*)(s + base);
    const float4* mv4 = (const float4*)(m + base);
    float4*       ov4 = (float4*)(out + base);

    // ---- issue all 8 global loads up front (64 B/lane outstanding) --------
    float4 sv[V4T], mv[V4T];
    #pragma unroll
    for (int t = 0; t < V4T; ++t) sv[t] = sv4[t * BLOCK + tid];
    #pragma unroll
    for (int t = 0; t < V4T; ++t) mv[t] = mv4[t * BLOCK + tid];

    // ---- gate + scale in registers; thread-local max ----------------------
    float4 zz[V4T];
    float zmax = -3.4028235e38f;
    #pragma unroll
    for (int t = 0; t < V4T; ++t) {
        float4 zv;
        zv.x = (mv[t].x > 0.5f ? sv[t].x : BIG_NEG) * INV_TAU;
        zv.y = (mv[t].y > 0.5f ? sv[t].y : BIG_NEG) * INV_TAU;
        zv.z = (mv[t].z > 0.5f ? sv[t].z : BIG_NEG) * INV_TAU;
        zv.w = (mv[t].w > 0.5f ? sv[t].w : BIG_NEG) * INV_TAU;
        zz[t] = zv;
        zmax = fmaxf(zmax, fmaxf(fmaxf(zv.x, zv.y), fmaxf(zv.z, zv.w)));
    }

    // ---- block-wide max: wave butterfly -> 4 LDS words -> combine ---------
    #pragma unroll
    for (int off = 32; off >= 1; off >>= 1)
        zmax = fmaxf(zmax, __shfl_xor(zmax, off, 64));
    if (lane == 0) red_max[wid] = zmax;
    __syncthreads();
    zmax = fmaxf(fmaxf(red_max[0], red_max[1]), fmaxf(red_max[2], red_max[3]));

    // ---- Michelot iterations (exact sparsemax threshold) ------------------
    // All threads compute identical S, C, tnew (same LDS reads, same order),
    // so the break is block-uniform and barrier-safe.
    float tau = zmax - 1.0f;
    for (int it = 0; it < 50; ++it) {
        float ssum = 0.0f, cnt = 0.0f;
        #pragma unroll
        for (int t = 0; t < V4T; ++t) {
            const float4 zv = zz[t];
            if (zv.x > tau) { ssum += zv.x; cnt += 1.0f; }
            if (zv.y > tau) { ssum += zv.y; cnt += 1.0f; }
            if (zv.z > tau) { ssum += zv.z; cnt += 1.0f; }
            if (zv.w > tau) { ssum += zv.w; cnt += 1.0f; }
        }
        #pragma unroll
        for (int off = 32; off >= 1; off >>= 1) {
            ssum += __shfl_xor(ssum, off, 64);
            cnt  += __shfl_xor(cnt,  off, 64);
        }
        __syncthreads();                 // previous iteration's reads complete
        if (lane == 0) { red_sum[wid] = ssum; red_cnt[wid] = cnt; }
        __syncthreads();
        const float S = ((red_sum[0] + red_sum[1]) + (red_sum[2] + red_sum[3]));
        const float C = ((red_cnt[0] + red_cnt[1]) + (red_cnt[2] + red_cnt[3]));
        const float tnew = (S - 1.0f) / C;   // C >= 1: the max is always in support
        if (tnew == tau) break;              // exact fixed point, block-uniform
        tau = tnew;
    }

    // ---- epilogue: out = min(k * max(z - tau, 0), 1) ----------------------
    #pragma unroll
    for (int t = 0; t < V4T; ++t) {
        const float4 zv = zz[t];
        float4 ov;
        ov.x = fminf(kf * fmaxf(zv.x - tau, 0.0f), 1.0f);
        ov.y = fminf(kf * fmaxf(zv.y - tau, 0.0f), 1.0f);
        ov.z = fminf(kf * fmaxf(zv.z - tau, 0.0f), 1.0f);
        ov.w = fminf(kf * fmaxf(zv.w - tau, 0.0f), 1.0f);
        ov4[t * BLOCK + tid] = ov;
    }
}

extern "C" void kernel_launch(void* const* d_in, const int* in_sizes, int n_in,
                              void* d_out, int out_size, void* d_ws, size_t ws_size,
                              hipStream_t stream) {
    const float* s = (const float*)d_in[0];
    const float* m = (const float*)d_in[1];
    const int*   k = (const int*)d_in[2];
    float* out = (float*)d_out;

    const int nrows = in_sizes[0] / R_DIM;   // 8192 rows -> 8192 blocks
    gate_sparsemax_k_kernel<<<nrows, BLOCK, 0, stream>>>(s, m, k, out);
}

// Round 5
// 293.802 us; speedup vs baseline: 1.0881x; 1.0635x over previous
//
#include <hip/hip_runtime.h>

// GateSparsemaxK: per-row (R=4096) gated sparsemax, scaled by k, clipped to [0,1].
// z = where(mask>0.5, s, -1e9)/0.7 ; p = sparsemax(z) ; out = min(k*p, 1)
//
// R3 post-mortem: VGPR_Count=20 proved the compiler serialized the 8 staging
// loads (sink-into-use), leaving ~1-2 loads/thread in flight -> 2.3 TB/s MLP-
// starved plateau across R1-R3. This version:
//  1. __builtin_amdgcn_sched_barrier(0) after the load block: all 8 float4
//     loads must issue before any compute -> 32 staging VGPRs, 8-deep MLP.
//     __launch_bounds__(256,4) gives the allocator headroom (<=128 VGPRs).
//  2. Ping-pong LDS reduction slots: 1 barrier per Michelot iter instead of 2.
//  3. Nontemporal loads/stores (pure streaming; don't evict L3) — via clang
//     ext_vector_type float4 alias, since the builtin rejects HIP_vector_type.

#define R_DIM 4096
#define BLOCK 256
#define V4T   4                 // float4s per thread: 4096 / 4 / 256
#define BIG_NEG -1.0e9f
#define INV_TAU (1.0f / 0.7f)

typedef float fx4 __attribute__((ext_vector_type(4)));   // builtin-compatible float4

__global__ __launch_bounds__(BLOCK, 4)
void gate_sparsemax_k_kernel(const float* __restrict__ s,
                             const float* __restrict__ m,
                             const int*  __restrict__ kptr,
                             float* __restrict__ out)
{
    __shared__ float red_sum[2][4];   // ping-pong slots (WAR-safe with 1 barrier)
    __shared__ float red_cnt[2][4];
    __shared__ float red_max[4];

    const int tid  = (int)threadIdx.x;
    const int lane = tid & 63;
    const int wid  = tid >> 6;
    const int row  = (int)blockIdx.x;

    const float kf = (float)(*kptr);

    const size_t base = (size_t)row * R_DIM;
    const fx4* sv4 = (const fx4*)(s + base);
    const fx4* mv4 = (const fx4*)(m + base);
    fx4*       ov4 = (fx4*)(out + base);

    // ---- issue ALL 8 global loads before any use --------------------------
    fx4 sv[V4T], mv[V4T];
    #pragma unroll
    for (int t = 0; t < V4T; ++t) sv[t] = __builtin_nontemporal_load(&sv4[t * BLOCK + tid]);
    #pragma unroll
    for (int t = 0; t < V4T; ++t) mv[t] = __builtin_nontemporal_load(&mv4[t * BLOCK + tid]);
    __builtin_amdgcn_sched_barrier(0);   // nothing crosses: loads stay grouped above

    // ---- gate + scale in registers; thread-local max ----------------------
    fx4 zz[V4T];
    float zmax = -3.4028235e38f;
    #pragma unroll
    for (int t = 0; t < V4T; ++t) {
        fx4 zv;
        zv.x = (mv[t].x > 0.5f ? sv[t].x : BIG_NEG) * INV_TAU;
        zv.y = (mv[t].y > 0.5f ? sv[t].y : BIG_NEG) * INV_TAU;
        zv.z = (mv[t].z > 0.5f ? sv[t].z : BIG_NEG) * INV_TAU;
        zv.w = (mv[t].w > 0.5f ? sv[t].w : BIG_NEG) * INV_TAU;
        zz[t] = zv;
        zmax = fmaxf(zmax, fmaxf(fmaxf(zv.x, zv.y), fmaxf(zv.z, zv.w)));
    }

    // ---- block-wide max: wave butterfly -> 4 LDS words -> combine ---------
    #pragma unroll
    for (int off = 32; off >= 1; off >>= 1)
        zmax = fmaxf(zmax, __shfl_xor(zmax, off, 64));
    if (lane == 0) red_max[wid] = zmax;
    __syncthreads();
    zmax = fmaxf(fmaxf(red_max[0], red_max[1]), fmaxf(red_max[2], red_max[3]));

    // ---- Michelot iterations (exact sparsemax threshold, no sort) ---------
    // tau0 = max-1 <= tau*; tau <- (sum_{z>tau} z - 1)/#{z>tau}. Monotone,
    // support shrinks, terminates exactly when support stabilizes. All threads
    // compute identical S,C,tnew -> block-uniform break, barrier-safe.
    float tau = zmax - 1.0f;
    for (int it = 0; it < 50; ++it) {
        float ssum = 0.0f, cnt = 0.0f;
        #pragma unroll
        for (int t = 0; t < V4T; ++t) {
            const fx4 zv = zz[t];
            if (zv.x > tau) { ssum += zv.x; cnt += 1.0f; }
            if (zv.y > tau) { ssum += zv.y; cnt += 1.0f; }
            if (zv.z > tau) { ssum += zv.z; cnt += 1.0f; }
            if (zv.w > tau) { ssum += zv.w; cnt += 1.0f; }
        }
        #pragma unroll
        for (int off = 32; off >= 1; off >>= 1) {
            ssum += __shfl_xor(ssum, off, 64);
            cnt  += __shfl_xor(cnt,  off, 64);
        }
        const int p = it & 1;
        if (lane == 0) { red_sum[p][wid] = ssum; red_cnt[p][wid] = cnt; }
        __syncthreads();   // single barrier: ping-pong slot avoids WAR on prev iter
        const float S = ((red_sum[p][0] + red_sum[p][1]) + (red_sum[p][2] + red_sum[p][3]));
        const float C = ((red_cnt[p][0] + red_cnt[p][1]) + (red_cnt[p][2] + red_cnt[p][3]));
        const float tnew = (S - 1.0f) / C;   // C >= 1: the max is always in support
        if (tnew == tau) break;              // exact fixed point, block-uniform
        tau = tnew;
    }

    // ---- epilogue: out = min(k * max(z - tau, 0), 1), nontemporal ---------
    #pragma unroll
    for (int t = 0; t < V4T; ++t) {
        const fx4 zv = zz[t];
        fx4 ov;
        ov.x = fminf(kf * fmaxf(zv.x - tau, 0.0f), 1.0f);
        ov.y = fminf(kf * fmaxf(zv.y - tau, 0.0f), 1.0f);
        ov.z = fminf(kf * fmaxf(zv.z - tau, 0.0f), 1.0f);
        ov.w = fminf(kf * fmaxf(zv.w - tau, 0.0f), 1.0f);
        __builtin_nontemporal_store(ov, &ov4[t * BLOCK + tid]);
    }
}

extern "C" void kernel_launch(void* const* d_in, const int* in_sizes, int n_in,
                              void* d_out, int out_size, void* d_ws, size_t ws_size,
                              hipStream_t stream) {
    const float* s = (const float*)d_in[0];
    const float* m = (const float*)d_in[1];
    const int*   k = (const int*)d_in[2];
    float* out = (float*)d_out;

    const int nrows = in_sizes[0] / R_DIM;   // 8192 rows -> 8192 blocks
    gate_sparsemax_k_kernel<<<nrows, BLOCK, 0, stream>>>(s, m, k, out);
}